// Round 3
// baseline (647.917 us; speedup 1.0000x reference)
//
#include <hip/hip_runtime.h>
#include <cstdint>
#include <cstddef>

#define E_DIM 1024
#define PD 64            // proj dim
#define NP 128           // 2*proj dim
#define B_DIM 8
#define S_DIM 2048
#define M_TOT (B_DIM * S_DIM)   // 16384

#define KH 512           // K per split-half
#define BM 64
#define BK 32
#define NCH (KH / BK)    // 16 chunks per half

__device__ __forceinline__ void gload16(const float* g, float* l) {
    __builtin_amdgcn_global_load_lds(
        (const __attribute__((address_space(1))) unsigned int*)g,
        (__attribute__((address_space(3))) unsigned int*)(uintptr_t)l,
        16, 0, 0);
}

// ---------------- K1: split-K GEMM partials (no bias) ----------------
// qkP[m][p] = sum_{k in half} A[m][k] * W[p][k];  A = context as (S*B,E), m = s*B+b
// 256 threads, per-thread 8 rows x 4 contiguous cols. B tile chunk-XOR swizzled.
__global__ __launch_bounds__(256, 2) void gemm_qk(const float* __restrict__ A,
                                                  const float* __restrict__ W,
                                                  float* __restrict__ qk0,
                                                  float* __restrict__ qk1) {
    __shared__ float As[2][BM][BK];    // [row][k], linear for global_load_lds
    __shared__ float Bs[2][BK][NP];    // [k][swizzled col]
    const int tid = threadIdx.x;
    const int kh  = blockIdx.x & 1;
    const int m0  = (blockIdx.x >> 1) * BM;
    const int k0  = kh * KH;
    const int wv  = tid >> 6;
    const int ln  = tid & 63;
    const int tyr = tid >> 5;       // 0..7  -> rows tyr*8..+7
    const int txc = tid & 31;       // 0..31 -> cols txc*4..+3 (via swizzle)
    const int q   = tid >> 3;       // 0..31  B staging row base
    const int sk4 = (tid & 7) * 4;  // staging k offset

    float* qkP = kh ? qk1 : qk0;

    const float* aG = A + (size_t)(m0 + wv * 8 + (ln >> 3)) * E_DIM + k0 + (ln & 7) * 4;
    const float* wG = W + (size_t)q * E_DIM + k0 + sk4;

    float acc[8][4];
#pragma unroll
    for (int i = 0; i < 8; ++i)
#pragma unroll
        for (int j = 0; j < 4; ++j) acc[i][j] = 0.f;

    float4 wr[4];

    // prologue: stage chunk 0 into buf 0
    gload16(aG, &As[0][wv * 8][0] + ln * 4);
    gload16(aG + 32 * E_DIM, &As[0][32 + wv * 8][0] + ln * 4);
#pragma unroll
    for (int j = 0; j < 4; ++j) wr[j] = *(const float4*)(wG + j * 32 * E_DIM);
#pragma unroll
    for (int j = 0; j < 4; ++j) {
        const int pr = q + 32 * j;
#pragma unroll
        for (int i = 0; i < 4; ++i) {
            const int k = sk4 + i;
            const int col = (((pr >> 2) ^ k) & 31) * 4 + (pr & 3);
            Bs[0][k][col] = ((const float*)&wr[j])[i];
        }
    }

    for (int ch = 0; ch < NCH; ++ch) {
        const int buf = ch & 1;
        const int nb = buf ^ 1;
        __syncthreads();
        if (ch + 1 < NCH) {
            const float* ga = aG + (ch + 1) * BK;
            gload16(ga, &As[nb][wv * 8][0] + ln * 4);
            gload16(ga + 32 * E_DIM, &As[nb][32 + wv * 8][0] + ln * 4);
            const float* gw = wG + (ch + 1) * BK;
#pragma unroll
            for (int j = 0; j < 4; ++j) wr[j] = *(const float4*)(gw + j * 32 * E_DIM);
        }
#pragma unroll
        for (int g = 0; g < 8; ++g) {
            float4 a[8];
#pragma unroll
            for (int i = 0; i < 8; ++i)
                a[i] = *(const float4*)&As[buf][tyr * 8 + i][g * 4];
#pragma unroll
            for (int kk = 0; kk < 4; ++kk) {
                const int k = g * 4 + kk;
                const float4 bv = *(const float4*)&Bs[buf][k][((txc ^ k) & 31) * 4];
#pragma unroll
                for (int i = 0; i < 8; ++i) {
                    const float av = ((const float*)&a[i])[kk];
                    acc[i][0] += av * bv.x;
                    acc[i][1] += av * bv.y;
                    acc[i][2] += av * bv.z;
                    acc[i][3] += av * bv.w;
                }
            }
        }
        if (ch + 1 < NCH) {
#pragma unroll
            for (int j = 0; j < 4; ++j) {
                const int pr = q + 32 * j;
#pragma unroll
                for (int i = 0; i < 4; ++i) {
                    const int k = sk4 + i;
                    const int col = (((pr >> 2) ^ k) & 31) * 4 + (pr & 3);
                    Bs[nb][k][col] = ((const float*)&wr[j])[i];
                }
            }
        }
    }

#pragma unroll
    for (int i = 0; i < 8; ++i) {
        float4 o;
        o.x = acc[i][0]; o.y = acc[i][1]; o.z = acc[i][2]; o.w = acc[i][3];
        *(float4*)&qkP[(size_t)(m0 + tyr * 8 + i) * NP + txc * 4] = o;
    }
}

// ---------------- K2: sum partials + bias, neighbor scores, 2-way softmax ----------------
__global__ __launch_bounds__(256) void neighbor_probs(const float* __restrict__ qk0,
                                                      const float* __restrict__ qk1,
                                                      const float* __restrict__ bias,
                                                      float* __restrict__ p0,
                                                      float* __restrict__ p1) {
    const int m = blockIdx.x * 4 + (threadIdx.x >> 6);  // position index m = s*B+b
    const int lane = threadIdx.x & 63;
    const int s = m >> 3;   // / B_DIM
    const int b = m & 7;    // % B_DIM

    const float bq = bias[lane];
    const float bk = bias[PD + lane];
    const float q = qk0[(size_t)m * NP + lane] + qk1[(size_t)m * NP + lane] + bq;
    float kn = 0.f, kp = 0.f;
    if (s < S_DIM - 1) {
        const size_t o = (size_t)(m + B_DIM) * NP + PD + lane;
        kn = qk0[o] + qk1[o] + bk;
    }
    if (s > 0) {
        const size_t o = (size_t)(m - B_DIM) * NP + PD + lane;
        kp = qk0[o] + qk1[o] + bk;
    }
    float f = q * kn;   // fwd partial: query[s] . key[s+1]
    float g = q * kp;   // bwd partial: query[s] . key[s-1]
#pragma unroll
    for (int off = 32; off; off >>= 1) {
        f += __shfl_xor(f, off);
        g += __shfl_xor(g, off);
    }
    if (lane == 0) {
        const float s0 = f * (1.f / (float)E_DIM);
        const float s1 = g * (1.f / (float)E_DIM);
        float P0, P1;
        if (s == S_DIM - 1) { P0 = 0.f; P1 = 1.f; }
        else if (s == 0)    { P0 = 1.f; P1 = 0.f; }
        else {
            const float mx = fmaxf(s0, s1);
            const float e0 = __expf(s0 - mx), e1 = __expf(s1 - mx);
            const float inv = 1.f / (e0 + e1);
            P0 = e0 * inv; P1 = e1 * inv;
        }
        p0[b * S_DIM + s] = P0;
        p1[b * S_DIM + s] = P1;
    }
}

// ---------------- K3: combine (flat roll), neighbor_attn out, log, exclusive scan ----------------
__global__ __launch_bounds__(256) void combine_scan(const float* __restrict__ p0,
                                                    const float* __restrict__ p1,
                                                    const float* __restrict__ prior,
                                                    float* __restrict__ out_na,
                                                    float* __restrict__ cs) {
    const int b = blockIdx.x;
    const int tid = threadIdx.x;
    __shared__ float sh[256];

    const int base = b * S_DIM + tid * 8;
    float incl[8];
    float run = 0.f;
#pragma unroll
    for (int u = 0; u < 8; ++u) {
        const int fidx = base + u;
        int nf = fidx + 1;
        if (nf == B_DIM * S_DIM) nf = 0;   // torch .roll on flattened tensor wraps globally
        const float P0 = p0[fidx];
        const float sp = p1[nf];
        const float pr = prior[fidx];
        const float na = pr + (1.f - pr) * sqrtf(P0 * sp + 1e-6f);
        out_na[fidx] = na;
        run += __logf(na);
        incl[u] = run;
    }
    sh[tid] = run;
    __syncthreads();
    for (int off = 1; off < 256; off <<= 1) {
        float v = sh[tid];
        if (tid >= off) v += sh[tid - off];
        __syncthreads();
        sh[tid] = v;
        __syncthreads();
    }
    const float offset = (tid > 0) ? sh[tid - 1] : 0.f;
#pragma unroll
    for (int u = 0; u < 8; ++u) {
        cs[base + u] = offset + ((u > 0) ? incl[u - 1] : 0.f);  // exclusive prefix
    }
}

// ---------------- K4: big output C[b,i,j] = exp(sign*(cs[j]-cs[i])), 0 on diag ----------------
__global__ __launch_bounds__(256) void big_out(const float* __restrict__ cs,
                                               float* __restrict__ out) {
    const int bi = blockIdx.x;          // b*S + i
    const int b = bi >> 11;             // / S_DIM
    const int i = bi & (S_DIM - 1);
    const float ci = cs[b * S_DIM + i];
    const float* crow = cs + (size_t)b * S_DIM;
    float* orow = out + (size_t)bi * S_DIM;
    const int j0 = threadIdx.x * 8;
#pragma unroll
    for (int h = 0; h < 2; ++h) {
        const int j = j0 + h * 4;
        const float4 cj = *(const float4*)&crow[j];
        float4 o;
        {
            const int jj = j + 0; const float m = (jj > i) ? (cj.x - ci) : (ci - cj.x);
            o.x = (jj == i) ? 0.f : __expf(m);
        }
        {
            const int jj = j + 1; const float m = (jj > i) ? (cj.y - ci) : (ci - cj.y);
            o.y = (jj == i) ? 0.f : __expf(m);
        }
        {
            const int jj = j + 2; const float m = (jj > i) ? (cj.z - ci) : (ci - cj.z);
            o.z = (jj == i) ? 0.f : __expf(m);
        }
        {
            const int jj = j + 3; const float m = (jj > i) ? (cj.w - ci) : (ci - cj.w);
            o.w = (jj == i) ? 0.f : __expf(m);
        }
        *(float4*)&orow[j] = o;
    }
}

extern "C" void kernel_launch(void* const* d_in, const int* in_sizes, int n_in,
                              void* d_out, int out_size, void* d_ws, size_t ws_size,
                              hipStream_t stream) {
    const float* context = (const float*)d_in[0];   // (S,B,E) fp32
    const float* prior   = (const float*)d_in[1];   // (B,S) fp32
    const float* W       = (const float*)d_in[2];   // (128,1024) fp32
    const float* bias    = (const float*)d_in[3];   // (128,) fp32
    float* out = (float*)d_out;

    float* qk0 = (float*)d_ws;                         // 16384*128 floats
    float* p0  = qk0 + (size_t)M_TOT * NP;             // 16384 floats
    float* p1  = p0 + M_TOT;                           // 16384 floats
    float* cs  = p1 + M_TOT;                           // 16384 floats
    // second partial lives in d_out's C-region; K4 overwrites it afterwards
    float* qk1 = out;
    float* na_out = out + (size_t)B_DIM * S_DIM * S_DIM;  // second output

    gemm_qk<<<(M_TOT / BM) * 2, 256, 0, stream>>>(context, W, qk0, qk1);
    neighbor_probs<<<M_TOT / 4, 256, 0, stream>>>(qk0, qk1, bias, p0, p1);
    combine_scan<<<B_DIM, 256, 0, stream>>>(p0, p1, prior, na_out, cs);
    big_out<<<M_TOT, 256, 0, stream>>>(cs, out);
}

// Round 4
// 608.438 us; speedup vs baseline: 1.0649x; 1.0649x over previous
//
#include <hip/hip_runtime.h>
#include <cstdint>
#include <cstddef>

#define E_DIM 1024
#define PD 64            // proj dim
#define NP 128           // 2*proj dim
#define B_DIM 8
#define S_DIM 2048
#define M_TOT (B_DIM * S_DIM)   // 16384

#define KH 512           // K per split-half
#define BM 64
#define BK 32
#define NCH (KH / BK)    // 16 chunks per half

__device__ __forceinline__ void gload16(const float* g, float* l) {
    __builtin_amdgcn_global_load_lds(
        (const __attribute__((address_space(1))) unsigned int*)g,
        (__attribute__((address_space(3))) unsigned int*)(uintptr_t)l,
        16, 0, 0);
}

// ---------------- K1: split-K GEMM partials (no bias) ----------------
// qkP[m][p] = sum_{k in half} A[m][k] * W[p][k];  A = context as (S*B,E), m = s*B+b
// 256 threads, per-thread 8 rows x 4 cols, 128 FMA per 12 ds_read_b128.
// As: [row][k] linear (global_load_lds, WAVE-UNIFORM base), source pre-swizzled
//     so slot (r,g) holds global granule g ^ ((r>>3)&7)  -> A reads conflict-free.
// Bs: [col][k] col-major, slot (c,g) holds granule g ^ (((c>>2)^c)&7)
//     -> stores conflict-free, reads at the structural 4-way floor.
__global__ __launch_bounds__(256, 2) void gemm_qk(const float* __restrict__ A,
                                                  const float* __restrict__ W,
                                                  float* __restrict__ qk0,
                                                  float* __restrict__ qk1) {
    __shared__ float As[2][BM][BK];
    __shared__ float Bs[2][NP][BK];
    const int tid = threadIdx.x;
    const int kh  = blockIdx.x & 1;
    const int m0  = (blockIdx.x >> 1) * BM;
    const int k0  = kh * KH;
    const int ln  = tid & 63;
    const int wvu = __builtin_amdgcn_readfirstlane(tid >> 6);  // wave id, provably scalar
    const int tyr = tid >> 5;       // 0..7  -> rows tyr*8..+7
    const int txc = tid & 31;       // 0..31 -> cols txc*4..+3
    const int q   = tid >> 3;       // 0..31  W staging row
    const int g8  = tid & 7;        // staging k-granule

    float* qkP = kh ? qk1 : qk0;

    // A staging: wave wvu covers local rows wvu*8..+7 (call 0) and +32 (call 1).
    // lane ln -> row wvu*8 + (ln>>3), slot granule ln&7, global granule (ln&7)^key
    const int arow = m0 + wvu * 8 + (ln >> 3);
    const float* aG0 = A + (size_t)arow * E_DIM + k0 + (((ln & 7) ^ (wvu & 7)) << 2);
    const float* aG1 = A + (size_t)(arow + 32) * E_DIM + k0 + (((ln & 7) ^ ((wvu + 4) & 7)) << 2);
    const float* wG  = W + (size_t)q * E_DIM + k0 + g8 * 4;

    // B store slots (per thread, 4 cols: q+32j)
    int bslot[4];
#pragma unroll
    for (int j = 0; j < 4; ++j) {
        const int col = q + 32 * j;
        const int key = ((col >> 2) ^ col) & 7;
        bslot[j] = col * BK + ((g8 ^ key) << 2);
    }
    // B read slots key per col
    int rkey[4];
#pragma unroll
    for (int c = 0; c < 4; ++c) {
        const int col = txc * 4 + c;
        rkey[c] = ((col >> 2) ^ col) & 7;
    }

    float acc[8][4];
#pragma unroll
    for (int i = 0; i < 8; ++i)
#pragma unroll
        for (int j = 0; j < 4; ++j) acc[i][j] = 0.f;

    float4 wr[4];

    // prologue: stage chunk 0 into buf 0
    gload16(aG0, &As[0][wvu * 8][0]);
    gload16(aG1, &As[0][wvu * 8 + 32][0]);
#pragma unroll
    for (int j = 0; j < 4; ++j) wr[j] = *(const float4*)(wG + j * 32 * E_DIM);
#pragma unroll
    for (int j = 0; j < 4; ++j) *(float4*)&Bs[0][0][bslot[j]] = wr[j];

    for (int ch = 0; ch < NCH; ++ch) {
        const int buf = ch & 1;
        const int nb = buf ^ 1;
        __syncthreads();
        if (ch + 1 < NCH) {
            const int off = (ch + 1) * BK;
            gload16(aG0 + off, &As[nb][wvu * 8][0]);
            gload16(aG1 + off, &As[nb][wvu * 8 + 32][0]);
            const float* gw = wG + off;
#pragma unroll
            for (int j = 0; j < 4; ++j) wr[j] = *(const float4*)(gw + j * 32 * E_DIM);
        }
#pragma unroll
        for (int g = 0; g < 8; ++g) {
            float4 a[8];
#pragma unroll
            for (int i = 0; i < 8; ++i)
                a[i] = *(const float4*)&As[buf][tyr * 8 + i][((g ^ tyr) & 7) << 2];
            float4 b[4];
#pragma unroll
            for (int c = 0; c < 4; ++c)
                b[c] = *(const float4*)&Bs[buf][txc * 4 + c][((g ^ rkey[c]) & 7) << 2];
#pragma unroll
            for (int kk = 0; kk < 4; ++kk) {
#pragma unroll
                for (int i = 0; i < 8; ++i) {
                    const float av = ((const float*)&a[i])[kk];
                    acc[i][0] += av * ((const float*)&b[0])[kk];
                    acc[i][1] += av * ((const float*)&b[1])[kk];
                    acc[i][2] += av * ((const float*)&b[2])[kk];
                    acc[i][3] += av * ((const float*)&b[3])[kk];
                }
            }
        }
        if (ch + 1 < NCH) {
#pragma unroll
            for (int j = 0; j < 4; ++j) *(float4*)&Bs[nb][0][bslot[j]] = wr[j];
        }
    }

#pragma unroll
    for (int i = 0; i < 8; ++i) {
        float4 o;
        o.x = acc[i][0]; o.y = acc[i][1]; o.z = acc[i][2]; o.w = acc[i][3];
        *(float4*)&qkP[(size_t)(m0 + tyr * 8 + i) * NP + txc * 4] = o;
    }
}

// ---------------- K2: sum partials + bias, neighbor scores, 2-way softmax ----------------
__global__ __launch_bounds__(256) void neighbor_probs(const float* __restrict__ qk0,
                                                      const float* __restrict__ qk1,
                                                      const float* __restrict__ bias,
                                                      float* __restrict__ p0,
                                                      float* __restrict__ p1) {
    const int m = blockIdx.x * 4 + (threadIdx.x >> 6);  // position index m = s*B+b
    const int lane = threadIdx.x & 63;
    const int s = m >> 3;   // / B_DIM
    const int b = m & 7;    // % B_DIM

    const float bq = bias[lane];
    const float bk = bias[PD + lane];
    const float q = qk0[(size_t)m * NP + lane] + qk1[(size_t)m * NP + lane] + bq;
    float kn = 0.f, kp = 0.f;
    if (s < S_DIM - 1) {
        const size_t o = (size_t)(m + B_DIM) * NP + PD + lane;
        kn = qk0[o] + qk1[o] + bk;
    }
    if (s > 0) {
        const size_t o = (size_t)(m - B_DIM) * NP + PD + lane;
        kp = qk0[o] + qk1[o] + bk;
    }
    float f = q * kn;   // fwd partial: query[s] . key[s+1]
    float g = q * kp;   // bwd partial: query[s] . key[s-1]
#pragma unroll
    for (int off = 32; off; off >>= 1) {
        f += __shfl_xor(f, off);
        g += __shfl_xor(g, off);
    }
    if (lane == 0) {
        const float s0 = f * (1.f / (float)E_DIM);
        const float s1 = g * (1.f / (float)E_DIM);
        float P0, P1;
        if (s == S_DIM - 1) { P0 = 0.f; P1 = 1.f; }
        else if (s == 0)    { P0 = 1.f; P1 = 0.f; }
        else {
            const float mx = fmaxf(s0, s1);
            const float e0 = __expf(s0 - mx), e1 = __expf(s1 - mx);
            const float inv = 1.f / (e0 + e1);
            P0 = e0 * inv; P1 = e1 * inv;
        }
        p0[b * S_DIM + s] = P0;
        p1[b * S_DIM + s] = P1;
    }
}

// ---------------- K3: combine (flat roll), neighbor_attn out, log, exclusive scan ----------------
__global__ __launch_bounds__(256) void combine_scan(const float* __restrict__ p0,
                                                    const float* __restrict__ p1,
                                                    const float* __restrict__ prior,
                                                    float* __restrict__ out_na,
                                                    float* __restrict__ cs) {
    const int b = blockIdx.x;
    const int tid = threadIdx.x;
    __shared__ float sh[256];

    const int base = b * S_DIM + tid * 8;
    float incl[8];
    float run = 0.f;
#pragma unroll
    for (int u = 0; u < 8; ++u) {
        const int fidx = base + u;
        int nf = fidx + 1;
        if (nf == B_DIM * S_DIM) nf = 0;   // torch .roll on flattened tensor wraps globally
        const float P0 = p0[fidx];
        const float sp = p1[nf];
        const float pr = prior[fidx];
        const float na = pr + (1.f - pr) * sqrtf(P0 * sp + 1e-6f);
        out_na[fidx] = na;
        run += __logf(na);
        incl[u] = run;
    }
    sh[tid] = run;
    __syncthreads();
    for (int off = 1; off < 256; off <<= 1) {
        float v = sh[tid];
        if (tid >= off) v += sh[tid - off];
        __syncthreads();
        sh[tid] = v;
        __syncthreads();
    }
    const float offset = (tid > 0) ? sh[tid - 1] : 0.f;
#pragma unroll
    for (int u = 0; u < 8; ++u) {
        cs[base + u] = offset + ((u > 0) ? incl[u - 1] : 0.f);  // exclusive prefix
    }
}

// ---------------- K4: big output C[b,i,j] = exp(sign*(cs[j]-cs[i])), 0 on diag ----------------
__global__ __launch_bounds__(256) void big_out(const float* __restrict__ cs,
                                               float* __restrict__ out) {
    const int bi = blockIdx.x;          // b*S + i
    const int b = bi >> 11;             // / S_DIM
    const int i = bi & (S_DIM - 1);
    const float ci = cs[b * S_DIM + i];
    const float* crow = cs + (size_t)b * S_DIM;
    float* orow = out + (size_t)bi * S_DIM;
    const int j0 = threadIdx.x * 8;
#pragma unroll
    for (int h = 0; h < 2; ++h) {
        const int j = j0 + h * 4;
        const float4 cj = *(const float4*)&crow[j];
        float4 o;
        {
            const int jj = j + 0; const float m = (jj > i) ? (cj.x - ci) : (ci - cj.x);
            o.x = (jj == i) ? 0.f : __expf(m);
        }
        {
            const int jj = j + 1; const float m = (jj > i) ? (cj.y - ci) : (ci - cj.y);
            o.y = (jj == i) ? 0.f : __expf(m);
        }
        {
            const int jj = j + 2; const float m = (jj > i) ? (cj.z - ci) : (ci - cj.z);
            o.z = (jj == i) ? 0.f : __expf(m);
        }
        {
            const int jj = j + 3; const float m = (jj > i) ? (cj.w - ci) : (ci - cj.w);
            o.w = (jj == i) ? 0.f : __expf(m);
        }
        *(float4*)&orow[j] = o;
    }
}

extern "C" void kernel_launch(void* const* d_in, const int* in_sizes, int n_in,
                              void* d_out, int out_size, void* d_ws, size_t ws_size,
                              hipStream_t stream) {
    const float* context = (const float*)d_in[0];   // (S,B,E) fp32
    const float* prior   = (const float*)d_in[1];   // (B,S) fp32
    const float* W       = (const float*)d_in[2];   // (128,1024) fp32
    const float* bias    = (const float*)d_in[3];   // (128,) fp32
    float* out = (float*)d_out;

    float* qk0 = (float*)d_ws;                         // 16384*128 floats
    float* p0  = qk0 + (size_t)M_TOT * NP;             // 16384 floats
    float* p1  = p0 + M_TOT;                           // 16384 floats
    float* cs  = p1 + M_TOT;                           // 16384 floats
    // second partial lives in d_out's C-region; K4 overwrites it afterwards
    float* qk1 = out;
    float* na_out = out + (size_t)B_DIM * S_DIM * S_DIM;  // second output

    gemm_qk<<<(M_TOT / BM) * 2, 256, 0, stream>>>(context, W, qk0, qk1);
    neighbor_probs<<<M_TOT / 4, 256, 0, stream>>>(qk0, qk1, bias, p0, p1);
    combine_scan<<<B_DIM, 256, 0, stream>>>(p0, p1, prior, na_out, cs);
    big_out<<<M_TOT, 256, 0, stream>>>(cs, out);
}